// Round 10
// baseline (42.906 us; speedup 1.0000x reference)
//
#include <hip/hip_runtime.h>
#include <math.h>

#define NBLK 4096  // k_main: 4096 blocks x 256 thr; 8 threads/image, 32 images/block

// ws layout (floats): [0..8191] partial[4096 blocks][2] (sum, sumsq)

__device__ __forceinline__ float med3f(float a, float b, float c) {
  return __builtin_amdgcn_fmed3f(a, b, c);
}
__device__ __forceinline__ float min3f(float a, float b, float c) { return fminf(fminf(a, b), c); }
__device__ __forceinline__ float max3f(float a, float b, float c) { return fmaxf(fmaxf(a, b), c); }

// ---------------------------------------------------------------------------
// Fold shift + FC into W'[c] for pixel p (math validated on HW R1..R9).
__device__ __forceinline__ void fold_weights(int p, const float* __restrict__ fc_w,
                                             float sx, float sy, float* __restrict__ w8) {
  const int y = p >> 4, x = p & 15;
  const int dY = (sy > 1.0f) ? 2 : 1;
  const int dX = (sx > 1.0f) ? 2 : 1;
  const float wy1 = (float)dY - sy, wy0 = 1.0f - wy1;
  const float wx1 = (float)dX - sx, wx0 = 1.0f - wx1;
  const int   iys[2] = { y + dY - 1, y + dY };
  const float wys[2] = { wy1, wy0 };
  const int   jxs[2] = { x + dX - 1, x + dX };
  const float wxs[2] = { wx1, wx0 };
  #pragma unroll
  for (int c = 0; c < 8; ++c) {
    float acc = 0.0f;
    #pragma unroll
    for (int a = 0; a < 2; ++a) {
      if (iys[a] < 0 || iys[a] >= 8) continue;
      #pragma unroll
      for (int b = 0; b < 2; ++b) {
        if (jxs[b] < 0 || jxs[b] >= 16) continue;
        acc += wys[a] * wxs[b] * fc_w[c * 128 + iys[a] * 16 + jxs[b]];
      }
    }
    w8[c] = acc;
  }
}

// ---------------------------------------------------------------------------
// K1: 8 threads per image, one per row — R9's validated structure, but each
// row is fetched from HBM exactly ONCE (R9 fetched 3x): thread loads its own
// row (wave = contiguous 1KB transactions), stages it into an LDS tile
// [32][10][16] with zeroed border rows, syncs, reads up/dn neighbors from
// LDS (mid stays in registers). Vertical sort3 in place; horizontal median +
// f32 weight-dot from swizzled LDS; 3-round butterfly -> coalesced 256B/wave
// store. ~90 VGPR: no spill at the (256,2) cap of 128.
__global__ __launch_bounds__(256, 2) void k_main(const float* __restrict__ x,
                                                 const float* __restrict__ fcw,
                                                 const float* __restrict__ xs,
                                                 const float* __restrict__ ys,
                                                 float* __restrict__ out,
                                                 float* __restrict__ partial) {
  __shared__ float tile[32][10][16];  // [img][1+row][col], rows 0/9 zero borders (20KB)
  __shared__ float wlds[8][16][8];    // [row][j^row][c] f32 weights (4KB)
  __shared__ float sred[8];
  const int tid = threadIdx.x;
  const int w = tid >> 6, l = tid & 63;
  const int row = l & 7;
  const int g   = w * 8 + (l >> 3);   // block-local image 0..31
  const int img = blockIdx.x * 32 + g;
  const float* __restrict__ xi = x + (size_t)img * 128;

  // own-row load: wave covers 8 images x 8 rows contiguously -> 1KB/instr
  float mid[16];
  #pragma unroll
  for (int q = 0; q < 4; ++q)
    *(float4*)&mid[q * 4] = *(const float4*)&xi[row * 16 + q * 4];

  // zero border rows (rows 0 and 9 of each image): 1024 floats / 256 thr
  #pragma unroll
  for (int i = 0; i < 4; ++i) {
    const int idx = tid + 256 * i;        // 0..1023
    const int gz  = idx >> 5;             // image
    const int rr  = (idx >> 4) & 1;       // 0 -> row 0, 1 -> row 9
    tile[gz][rr * 9][idx & 15] = 0.0f;
  }

  // per-block W' fold into swizzled LDS (threads 0..127, pixel p = tid)
  const float sx = xs[0] + 0.5f, sy = ys[0] + 0.5f;
  if (tid < 128) {
    float w8[8];
    fold_weights(tid, fcw, sx, sy, w8);
    const int r = tid >> 4, j = tid & 15;
    #pragma unroll
    for (int c = 0; c < 8; ++c) wlds[r][j ^ r][c] = w8[c];
  }

  // stage own row for neighbors
  #pragma unroll
  for (int q = 0; q < 4; ++q)
    *(float4*)&tile[g][row + 1][q * 4] = *(const float4*)&mid[q * 4];
  __syncthreads();

  // neighbor rows from LDS (borders are zero rows -> no branches)
  float up[16], dn[16];
  #pragma unroll
  for (int q = 0; q < 4; ++q) {
    *(float4*)&up[q * 4] = *(const float4*)&tile[g][row][q * 4];
    *(float4*)&dn[q * 4] = *(const float4*)&tile[g][row + 2][q * 4];
  }

  // vertical sort3 IN PLACE
  #pragma unroll
  for (int k = 0; k < 16; ++k) {
    const float a = up[k], b = mid[k], d = dn[k];
    up[k]  = min3f(a, b, d);   // lo
    mid[k] = med3f(a, b, d);   // mi
    dn[k]  = max3f(a, b, d);   // hi
  }

  float acc[8];
  #pragma unroll
  for (int c = 0; c < 8; ++c) acc[c] = 0.0f;
  float ssum = 0.0f, ssq = 0.0f;

  #pragma unroll
  for (int j = 0; j < 16; ++j) {
    const float mx  = max3f((j == 0)  ? 0.0f : up[j - 1],  up[j],
                            (j == 15) ? 0.0f : up[j + 1]);
    const float md  = med3f((j == 0)  ? 0.0f : mid[j - 1], mid[j],
                            (j == 15) ? 0.0f : mid[j + 1]);
    const float mn  = min3f((j == 0)  ? 0.0f : dn[j - 1],  dn[j],
                            (j == 15) ? 0.0f : dn[j + 1]);
    const float med = med3f(mx, md, mn);  // exact lower-median of 9
    ssum += med;
    ssq = fmaf(med, med, ssq);
    const float* wp = &wlds[row][j ^ row][0];
    const float4 w0 = *(const float4*)&wp[0];
    const float4 w1 = *(const float4*)&wp[4];
    acc[0] = fmaf(med, w0.x, acc[0]);
    acc[1] = fmaf(med, w0.y, acc[1]);
    acc[2] = fmaf(med, w0.z, acc[2]);
    acc[3] = fmaf(med, w0.w, acc[3]);
    acc[4] = fmaf(med, w1.x, acc[4]);
    acc[5] = fmaf(med, w1.y, acc[5]);
    acc[6] = fmaf(med, w1.z, acc[6]);
    acc[7] = fmaf(med, w1.w, acc[7]);
  }

  // 3-round value-splitting butterfly over the 8 row-lanes (xor 4,2,1):
  // lane ends holding class (l&7) -> coalesced 256B/wave store.
  const bool b4 = (l & 4) != 0;
  float r4[4];
  #pragma unroll
  for (int j = 0; j < 4; ++j) {
    const float send = b4 ? acc[j] : acc[4 + j];
    const float keep = b4 ? acc[4 + j] : acc[j];
    r4[j] = keep + __shfl_xor(send, 4, 64);
  }
  const bool b2 = (l & 2) != 0;
  float r2[2];
  #pragma unroll
  for (int j = 0; j < 2; ++j) {
    const float send = b2 ? r4[j] : r4[2 + j];
    const float keep = b2 ? r4[2 + j] : r4[j];
    r2[j] = keep + __shfl_xor(send, 2, 64);
  }
  const bool b1 = (l & 1) != 0;
  {
    const float send = b1 ? r2[0] : r2[1];
    const float keep = b1 ? r2[1] : r2[0];
    const float r = keep + __shfl_xor(send, 1, 64);
    out[(size_t)img * 8 + (l & 7)] = r;
  }

  // stats: wave reduce then block reduce
  #pragma unroll
  for (int off = 32; off; off >>= 1) {
    ssum += __shfl_xor(ssum, off, 64);
    ssq  += __shfl_xor(ssq,  off, 64);
  }
  if (l == 0) { sred[w] = ssum; sred[4 + w] = ssq; }
  __syncthreads();
  if (tid == 0) partial[2 * blockIdx.x]     = (sred[0] + sred[1]) + (sred[2] + sred[3]);
  if (tid == 1) partial[2 * blockIdx.x + 1] = (sred[4] + sred[5]) + (sred[6] + sred[7]);
}

// ---------------------------------------------------------------------------
// K2: each of 256 blocks redundantly reduces partial[8192] (L2-hot),
// recomputes the f32 W' fold for per-class sums, then scales 4 float4/thread:
// out = alpha*dot + (beta*wsum[c] + fcb[c]).
__global__ __launch_bounds__(256) void k_scale(float* __restrict__ out,
                                               const float* __restrict__ partial,
                                               const float* __restrict__ fcw,
                                               const float* __restrict__ xs,
                                               const float* __restrict__ ys,
                                               const float* __restrict__ fcb,
                                               const float* __restrict__ bnw,
                                               const float* __restrict__ bnb) {
  __shared__ float sred[8];
  __shared__ float wred[4][8];
  __shared__ float fin[2];
  const int tid = threadIdx.x;
  const int w = tid >> 6, l = tid & 63;

  // batch stats: 4096 block-pairs / 256 threads = 16 each
  float s = 0.0f, q = 0.0f;
  #pragma unroll
  for (int k = 0; k < 16; ++k) {
    const int idx = tid + 256 * k;
    s += partial[2 * idx];
    q += partial[2 * idx + 1];
  }
  #pragma unroll
  for (int off = 32; off; off >>= 1) {
    s += __shfl_xor(s, off, 64);
    q += __shfl_xor(q, off, 64);
  }

  // redundant W' fold for per-class sums (threads 0..127 contribute)
  float v[8];
  if (tid < 128) {
    fold_weights(tid, fcw, xs[0] + 0.5f, ys[0] + 0.5f, v);
  } else {
    #pragma unroll
    for (int c = 0; c < 8; ++c) v[c] = 0.0f;
  }
  #pragma unroll
  for (int c = 0; c < 8; ++c) {
    #pragma unroll
    for (int off = 32; off; off >>= 1) v[c] += __shfl_xor(v[c], off, 64);
  }

  if (l == 0) {
    sred[w] = s; sred[4 + w] = q;
    #pragma unroll
    for (int c = 0; c < 8; ++c) wred[w][c] = v[c];
  }
  __syncthreads();
  if (tid == 0) {
    const float S = (sred[0] + sred[1]) + (sred[2] + sred[3]);
    const float Q = (sred[4] + sred[5]) + (sred[6] + sred[7]);
    const float N = 16777216.0f;  // 131072*128
    const float mm = S / N;
    const float vv = Q / N - mm * mm;
    const float a = bnw[0] / sqrtf(vv + 1e-5f);
    fin[0] = a;
    fin[1] = bnb[0] - mm * a;
  }
  __syncthreads();
  const float alpha = fin[0], beta = fin[1];

  float cv[8];
  #pragma unroll
  for (int c = 0; c < 8; ++c) {
    const float wsum = (wred[0][c] + wred[1][c]) + (wred[2][c] + wred[3][c]);
    cv[c] = fmaf(beta, wsum, fcb[c]);
  }
  const float4 cv0 = make_float4(cv[0], cv[1], cv[2], cv[3]);
  const float4 cv1 = make_float4(cv[4], cv[5], cv[6], cv[7]);

  float4* o4 = (float4*)out;
  const int base = (blockIdx.x * 256 + tid) * 4;  // 4 float4 per thread
  #pragma unroll
  for (int k = 0; k < 4; ++k) {
    const int i = base + k;
    const float4 c = (i & 1) ? cv1 : cv0;
    float4 ov = o4[i];
    ov.x = fmaf(alpha, ov.x, c.x);
    ov.y = fmaf(alpha, ov.y, c.y);
    ov.z = fmaf(alpha, ov.z, c.z);
    ov.w = fmaf(alpha, ov.w, c.w);
    o4[i] = ov;
  }
}

// ---------------------------------------------------------------------------
extern "C" void kernel_launch(void* const* d_in, const int* in_sizes, int n_in,
                              void* d_out, int out_size, void* d_ws, size_t ws_size,
                              hipStream_t stream) {
  const float* x   = (const float*)d_in[0];
  const float* bnw = (const float*)d_in[1];
  const float* bnb = (const float*)d_in[2];
  const float* xs  = (const float*)d_in[3];
  const float* ys  = (const float*)d_in[4];
  const float* fcw = (const float*)d_in[5];
  const float* fcb = (const float*)d_in[6];
  float* out = (float*)d_out;
  float* ws  = (float*)d_ws;

  float* partial = ws;  // 8192 floats

  hipLaunchKernelGGL(k_main,  dim3(NBLK), dim3(256), 0, stream, x, fcw, xs, ys, out, partial);
  hipLaunchKernelGGL(k_scale, dim3(256),  dim3(256), 0, stream, out, partial, fcw, xs, ys, fcb, bnw, bnb);
}

// Round 11
// 40.100 us; speedup vs baseline: 1.0700x; 1.0700x over previous
//
#include <hip/hip_runtime.h>
#include <math.h>

#define NBLK 4096  // k_main: 4096 blocks x 256 thr; 8 threads/image, 32 images/block

// ws layout (floats): [0..8191] partial[4096 blocks][2] (sum, sumsq)

__device__ __forceinline__ float med3f(float a, float b, float c) {
  return __builtin_amdgcn_fmed3f(a, b, c);
}
__device__ __forceinline__ float min3f(float a, float b, float c) { return fminf(fminf(a, b), c); }
__device__ __forceinline__ float max3f(float a, float b, float c) { return fmaxf(fmaxf(a, b), c); }

// ---------------------------------------------------------------------------
// Fold shift + FC into W'[c] for pixel p (math validated on HW R1..R10).
__device__ __forceinline__ void fold_weights(int p, const float* __restrict__ fc_w,
                                             float sx, float sy, float* __restrict__ w8) {
  const int y = p >> 4, x = p & 15;
  const int dY = (sy > 1.0f) ? 2 : 1;
  const int dX = (sx > 1.0f) ? 2 : 1;
  const float wy1 = (float)dY - sy, wy0 = 1.0f - wy1;
  const float wx1 = (float)dX - sx, wx0 = 1.0f - wx1;
  const int   iys[2] = { y + dY - 1, y + dY };
  const float wys[2] = { wy1, wy0 };
  const int   jxs[2] = { x + dX - 1, x + dX };
  const float wxs[2] = { wx1, wx0 };
  #pragma unroll
  for (int c = 0; c < 8; ++c) {
    float acc = 0.0f;
    #pragma unroll
    for (int a = 0; a < 2; ++a) {
      if (iys[a] < 0 || iys[a] >= 8) continue;
      #pragma unroll
      for (int b = 0; b < 2; ++b) {
        if (jxs[b] < 0 || jxs[b] >= 16) continue;
        acc += wys[a] * wxs[b] * fc_w[c * 128 + iys[a] * 16 + jxs[b]];
      }
    }
    w8[c] = acc;
  }
}

// ---------------------------------------------------------------------------
// K1: 8 threads per image, one per row. Neighbor rows come from ADJACENT
// LANES via __shfl_up/down(.,1,16) (DPP row_shr/row_shl — pure VALU, no LDS):
// lane l = w*8-group + (g<<3) + row, so up=lane-1, dn=lane+1; every shuffle
// that crosses an image boundary is exactly a row==0/row==7 case and gets
// zero-masked. This removes R10's 20KB tile whose 160-word image stride
// (~0 mod 32) caused 3.28M 8-way bank conflicts. Remaining LDS: 4KB weight
// table (XOR-swizzled, 2-way = free) + sred. ~75 VGPR, no spill.
__global__ __launch_bounds__(256, 2) void k_main(const float* __restrict__ x,
                                                 const float* __restrict__ fcw,
                                                 const float* __restrict__ xs,
                                                 const float* __restrict__ ys,
                                                 float* __restrict__ out,
                                                 float* __restrict__ partial) {
  __shared__ float wlds[8][16][8];  // [row][j^row][c] f32 weights (4KB)
  __shared__ float sred[8];
  const int tid = threadIdx.x;
  const int w = tid >> 6, l = tid & 63;
  const int row = l & 7;
  const int g   = w * 8 + (l >> 3);   // block-local image 0..31
  const int img = blockIdx.x * 32 + g;
  const float* __restrict__ xi = x + (size_t)img * 128;

  // own-row load: wave covers 8 images x 8 rows contiguously -> 1KB/instr
  float mid[16];
  #pragma unroll
  for (int q = 0; q < 4; ++q)
    *(float4*)&mid[q * 4] = *(const float4*)&xi[row * 16 + q * 4];

  // per-block W' fold into swizzled LDS (threads 0..127, pixel p = tid);
  // VALU work here covers the global-load latency
  const float sx = xs[0] + 0.5f, sy = ys[0] + 0.5f;
  if (tid < 128) {
    float w8[8];
    fold_weights(tid, fcw, sx, sy, w8);
    const int r = tid >> 4, j = tid & 15;
    #pragma unroll
    for (int c = 0; c < 8; ++c) wlds[r][j ^ r][c] = w8[c];
  }
  __syncthreads();

  // neighbor rows from adjacent lanes (DPP); boundary lanes zero-masked
  float up[16], dn[16];
  #pragma unroll
  for (int k = 0; k < 16; ++k) {
    const float u = __shfl_up(mid[k], 1, 16);
    const float d = __shfl_down(mid[k], 1, 16);
    up[k] = (row == 0) ? 0.0f : u;
    dn[k] = (row == 7) ? 0.0f : d;
  }

  // vertical sort3 IN PLACE
  #pragma unroll
  for (int k = 0; k < 16; ++k) {
    const float a = up[k], b = mid[k], d = dn[k];
    up[k]  = min3f(a, b, d);   // lo
    mid[k] = med3f(a, b, d);   // mi
    dn[k]  = max3f(a, b, d);   // hi
  }

  float acc[8];
  #pragma unroll
  for (int c = 0; c < 8; ++c) acc[c] = 0.0f;
  float ssum = 0.0f, ssq = 0.0f;

  #pragma unroll
  for (int j = 0; j < 16; ++j) {
    const float mx  = max3f((j == 0)  ? 0.0f : up[j - 1],  up[j],
                            (j == 15) ? 0.0f : up[j + 1]);
    const float md  = med3f((j == 0)  ? 0.0f : mid[j - 1], mid[j],
                            (j == 15) ? 0.0f : mid[j + 1]);
    const float mn  = min3f((j == 0)  ? 0.0f : dn[j - 1],  dn[j],
                            (j == 15) ? 0.0f : dn[j + 1]);
    const float med = med3f(mx, md, mn);  // exact lower-median of 9
    ssum += med;
    ssq = fmaf(med, med, ssq);
    const float* wp = &wlds[row][j ^ row][0];
    const float4 w0 = *(const float4*)&wp[0];  // 2-way max across rows = free
    const float4 w1 = *(const float4*)&wp[4];
    acc[0] = fmaf(med, w0.x, acc[0]);
    acc[1] = fmaf(med, w0.y, acc[1]);
    acc[2] = fmaf(med, w0.z, acc[2]);
    acc[3] = fmaf(med, w0.w, acc[3]);
    acc[4] = fmaf(med, w1.x, acc[4]);
    acc[5] = fmaf(med, w1.y, acc[5]);
    acc[6] = fmaf(med, w1.z, acc[6]);
    acc[7] = fmaf(med, w1.w, acc[7]);
  }

  // 3-round value-splitting butterfly over the 8 row-lanes (xor 4,2,1):
  // lane ends holding class (l&7) -> coalesced 256B/wave store.
  const bool b4 = (l & 4) != 0;
  float r4[4];
  #pragma unroll
  for (int j = 0; j < 4; ++j) {
    const float send = b4 ? acc[j] : acc[4 + j];
    const float keep = b4 ? acc[4 + j] : acc[j];
    r4[j] = keep + __shfl_xor(send, 4, 64);
  }
  const bool b2 = (l & 2) != 0;
  float r2[2];
  #pragma unroll
  for (int j = 0; j < 2; ++j) {
    const float send = b2 ? r4[j] : r4[2 + j];
    const float keep = b2 ? r4[2 + j] : r4[j];
    r2[j] = keep + __shfl_xor(send, 2, 64);
  }
  const bool b1 = (l & 1) != 0;
  {
    const float send = b1 ? r2[0] : r2[1];
    const float keep = b1 ? r2[1] : r2[0];
    const float r = keep + __shfl_xor(send, 1, 64);
    out[(size_t)img * 8 + (l & 7)] = r;
  }

  // stats: wave reduce then block reduce
  #pragma unroll
  for (int off = 32; off; off >>= 1) {
    ssum += __shfl_xor(ssum, off, 64);
    ssq  += __shfl_xor(ssq,  off, 64);
  }
  if (l == 0) { sred[w] = ssum; sred[4 + w] = ssq; }
  __syncthreads();
  if (tid == 0) partial[2 * blockIdx.x]     = (sred[0] + sred[1]) + (sred[2] + sred[3]);
  if (tid == 1) partial[2 * blockIdx.x + 1] = (sred[4] + sred[5]) + (sred[6] + sred[7]);
}

// ---------------------------------------------------------------------------
// K2: each of 256 blocks redundantly reduces partial[8192] (L2-hot),
// recomputes the f32 W' fold for per-class sums, then scales 4 float4/thread:
// out = alpha*dot + (beta*wsum[c] + fcb[c]).
__global__ __launch_bounds__(256) void k_scale(float* __restrict__ out,
                                               const float* __restrict__ partial,
                                               const float* __restrict__ fcw,
                                               const float* __restrict__ xs,
                                               const float* __restrict__ ys,
                                               const float* __restrict__ fcb,
                                               const float* __restrict__ bnw,
                                               const float* __restrict__ bnb) {
  __shared__ float sred[8];
  __shared__ float wred[4][8];
  __shared__ float fin[2];
  const int tid = threadIdx.x;
  const int w = tid >> 6, l = tid & 63;

  // batch stats: 4096 block-pairs / 256 threads = 16 each
  float s = 0.0f, q = 0.0f;
  #pragma unroll
  for (int k = 0; k < 16; ++k) {
    const int idx = tid + 256 * k;
    s += partial[2 * idx];
    q += partial[2 * idx + 1];
  }
  #pragma unroll
  for (int off = 32; off; off >>= 1) {
    s += __shfl_xor(s, off, 64);
    q += __shfl_xor(q, off, 64);
  }

  // redundant W' fold for per-class sums (threads 0..127 contribute)
  float v[8];
  if (tid < 128) {
    fold_weights(tid, fcw, xs[0] + 0.5f, ys[0] + 0.5f, v);
  } else {
    #pragma unroll
    for (int c = 0; c < 8; ++c) v[c] = 0.0f;
  }
  #pragma unroll
  for (int c = 0; c < 8; ++c) {
    #pragma unroll
    for (int off = 32; off; off >>= 1) v[c] += __shfl_xor(v[c], off, 64);
  }

  if (l == 0) {
    sred[w] = s; sred[4 + w] = q;
    #pragma unroll
    for (int c = 0; c < 8; ++c) wred[w][c] = v[c];
  }
  __syncthreads();
  if (tid == 0) {
    const float S = (sred[0] + sred[1]) + (sred[2] + sred[3]);
    const float Q = (sred[4] + sred[5]) + (sred[6] + sred[7]);
    const float N = 16777216.0f;  // 131072*128
    const float mm = S / N;
    const float vv = Q / N - mm * mm;
    const float a = bnw[0] / sqrtf(vv + 1e-5f);
    fin[0] = a;
    fin[1] = bnb[0] - mm * a;
  }
  __syncthreads();
  const float alpha = fin[0], beta = fin[1];

  float cv[8];
  #pragma unroll
  for (int c = 0; c < 8; ++c) {
    const float wsum = (wred[0][c] + wred[1][c]) + (wred[2][c] + wred[3][c]);
    cv[c] = fmaf(beta, wsum, fcb[c]);
  }
  const float4 cv0 = make_float4(cv[0], cv[1], cv[2], cv[3]);
  const float4 cv1 = make_float4(cv[4], cv[5], cv[6], cv[7]);

  float4* o4 = (float4*)out;
  const int base = (blockIdx.x * 256 + tid) * 4;  // 4 float4 per thread
  #pragma unroll
  for (int k = 0; k < 4; ++k) {
    const int i = base + k;
    const float4 c = (i & 1) ? cv1 : cv0;
    float4 ov = o4[i];
    ov.x = fmaf(alpha, ov.x, c.x);
    ov.y = fmaf(alpha, ov.y, c.y);
    ov.z = fmaf(alpha, ov.z, c.z);
    ov.w = fmaf(alpha, ov.w, c.w);
    o4[i] = ov;
  }
}

// ---------------------------------------------------------------------------
extern "C" void kernel_launch(void* const* d_in, const int* in_sizes, int n_in,
                              void* d_out, int out_size, void* d_ws, size_t ws_size,
                              hipStream_t stream) {
  const float* x   = (const float*)d_in[0];
  const float* bnw = (const float*)d_in[1];
  const float* bnb = (const float*)d_in[2];
  const float* xs  = (const float*)d_in[3];
  const float* ys  = (const float*)d_in[4];
  const float* fcw = (const float*)d_in[5];
  const float* fcb = (const float*)d_in[6];
  float* out = (float*)d_out;
  float* ws  = (float*)d_ws;

  float* partial = ws;  // 8192 floats

  hipLaunchKernelGGL(k_main,  dim3(NBLK), dim3(256), 0, stream, x, fcw, xs, ys, out, partial);
  hipLaunchKernelGGL(k_scale, dim3(256),  dim3(256), 0, stream, out, partial, fcw, xs, ys, fcb, bnw, bnb);
}

// Round 12
// 35.945 us; speedup vs baseline: 1.1937x; 1.1156x over previous
//
#include <hip/hip_runtime.h>
#include <math.h>

#define NBLK 4096  // k_main: 4096 blocks x 256 thr; 8 threads/image, 32 images/block

// ws layout (floats): [0..8191] partial[4096 blocks][2] (sum, sumsq)

typedef __attribute__((ext_vector_type(8))) short bf16x8;
typedef __attribute__((ext_vector_type(4))) float f32x4;

__device__ __forceinline__ float med3f(float a, float b, float c) {
  return __builtin_amdgcn_fmed3f(a, b, c);
}
__device__ __forceinline__ float min3f(float a, float b, float c) { return fminf(fminf(a, b), c); }
__device__ __forceinline__ float max3f(float a, float b, float c) { return fmaxf(fmaxf(a, b), c); }

__device__ __forceinline__ unsigned bf16rne(float f) {  // RNE f32->bf16 (finite)
  const unsigned b = __float_as_uint(f);
  return (b + 0x7fffu + ((b >> 16) & 1u)) >> 16;
}

// DPP neighbor exchange within 16-lane rows (pure VALU, no DS pipe).
// row_shr:1 (0x111): lane i <- lane i-1.  row_shl:1 (0x101): lane i <- lane i+1.
// Image groups are 8 lanes; every cross-image transfer is a row==0/row==7
// case and is zero-masked by the caller.
__device__ __forceinline__ float dpp_up(float v) {
  return __int_as_float(__builtin_amdgcn_update_dpp(0, __float_as_int(v), 0x111, 0xf, 0xf, true));
}
__device__ __forceinline__ float dpp_dn(float v) {
  return __int_as_float(__builtin_amdgcn_update_dpp(0, __float_as_int(v), 0x101, 0xf, 0xf, true));
}

// ---------------------------------------------------------------------------
// Fold shift + FC into W'[c] for pixel p (math validated on HW R1..R11).
__device__ __forceinline__ void fold_weights(int p, const float* __restrict__ fc_w,
                                             float sx, float sy, float* __restrict__ w8) {
  const int y = p >> 4, x = p & 15;
  const int dY = (sy > 1.0f) ? 2 : 1;
  const int dX = (sx > 1.0f) ? 2 : 1;
  const float wy1 = (float)dY - sy, wy0 = 1.0f - wy1;
  const float wx1 = (float)dX - sx, wx0 = 1.0f - wx1;
  const int   iys[2] = { y + dY - 1, y + dY };
  const float wys[2] = { wy1, wy0 };
  const int   jxs[2] = { x + dX - 1, x + dX };
  const float wxs[2] = { wx1, wx0 };
  #pragma unroll
  for (int c = 0; c < 8; ++c) {
    float acc = 0.0f;
    #pragma unroll
    for (int a = 0; a < 2; ++a) {
      if (iys[a] < 0 || iys[a] >= 8) continue;
      #pragma unroll
      for (int b = 0; b < 2; ++b) {
        if (jxs[b] < 0 || jxs[b] >= 16) continue;
        acc += wys[a] * wxs[b] * fc_w[c * 128 + iys[a] * 16 + jxs[b]];
      }
    }
    w8[c] = acc;
  }
}

// ---------------------------------------------------------------------------
// K1: Phase 1 — 8 thr/image, one per row; neighbors via DPP (VALU); medians
// in registers; meds -> bf16 pairs -> ONE swizzled 32B LDS write per thread.
// Phase 2 — waves 0,1 each compute a 16-image tile with 4x
// mfma_f32_16x16x32_bf16: A = W' bf16 [class][pixel] (read once), B = meds.
// A and B fragments use the SAME (lane,h,e)->pixel map, so the contraction is
// correct for any intra-fragment k-order. C/D: col=lane&15(img),
// row=(lane>>4)*4+reg(class); lanes 0-31 store out[img][0..7] as float4.
// Per-pixel weight reads: ZERO (was 32 ds_read_b128/wave in R11).
__global__ __launch_bounds__(256, 2) void k_main(const float* __restrict__ x,
                                                 const float* __restrict__ fcw,
                                                 const float* __restrict__ xs,
                                                 const float* __restrict__ ys,
                                                 float* __restrict__ out,
                                                 float* __restrict__ partial) {
  __shared__ unsigned short wlds[16][128];  // bf16 W'[class][pixel]; rows 8-15 = 0 (4KB)
  __shared__ unsigned medl[32][64];         // bf16-pair meds [img][dword], row-swizzled (8KB)
  __shared__ float sred[8];
  const int tid = threadIdx.x;
  const int w = tid >> 6, l = tid & 63;
  const int g   = tid >> 3;                 // block-local image 0..31
  const int row = tid & 7;
  const int img = blockIdx.x * 32 + g;

  // own-row load first (wave = contiguous 4KB)
  const float* __restrict__ xr = x + (size_t)img * 128 + row * 16;
  float mid[16];
  #pragma unroll
  for (int q = 0; q < 4; ++q)
    *(float4*)&mid[q * 4] = *(const float4*)&xr[q * 4];

  // weight fold -> bf16 LDS (VALU covers the global-load latency)
  const float sx = xs[0] + 0.5f, sy = ys[0] + 0.5f;
  if (tid < 128) {
    float w8[8];
    fold_weights(tid, fcw, sx, sy, w8);
    #pragma unroll
    for (int c = 0; c < 8; ++c) wlds[c][tid] = (unsigned short)bf16rne(w8[c]);
  } else {
    ((uint4*)&wlds[8][0])[tid - 128] = make_uint4(0, 0, 0, 0);  // classes 8-15 = 0
  }

  // neighbor rows via DPP; boundary rows zero-masked
  float up[16], dn[16];
  #pragma unroll
  for (int k = 0; k < 16; ++k) {
    const float u = dpp_up(mid[k]);
    const float d = dpp_dn(mid[k]);
    up[k] = (row == 0) ? 0.0f : u;
    dn[k] = (row == 7) ? 0.0f : d;
  }

  // vertical sort3 in place
  #pragma unroll
  for (int k = 0; k < 16; ++k) {
    const float a = up[k], b = mid[k], d = dn[k];
    up[k]  = min3f(a, b, d);
    mid[k] = med3f(a, b, d);
    dn[k]  = max3f(a, b, d);
  }

  // horizontal combine + stats (f32 exact meds for BN stats)
  float med[16];
  float ssum = 0.0f, ssq = 0.0f;
  #pragma unroll
  for (int j = 0; j < 16; ++j) {
    const float mx = max3f((j == 0)  ? 0.0f : up[j - 1],  up[j],
                           (j == 15) ? 0.0f : up[j + 1]);
    const float md = med3f((j == 0)  ? 0.0f : mid[j - 1], mid[j],
                           (j == 15) ? 0.0f : mid[j + 1]);
    const float mn = min3f((j == 0)  ? 0.0f : dn[j - 1],  dn[j],
                           (j == 15) ? 0.0f : dn[j + 1]);
    med[j] = med3f(mx, md, mn);  // exact lower-median of 9
    ssum += med[j];
    ssq = fmaf(med[j], med[j], ssq);
  }

  // pack meds to bf16 pairs; swizzled write (row ^ (img&7) spreads banks)
  {
    unsigned u[8];
    #pragma unroll
    for (int jj = 0; jj < 8; ++jj)
      u[jj] = bf16rne(med[2 * jj]) | (bf16rne(med[2 * jj + 1]) << 16);
    const int rsw = row ^ (g & 7);
    uint4* mdst = (uint4*)&medl[g][rsw * 8];
    mdst[0] = make_uint4(u[0], u[1], u[2], u[3]);
    mdst[1] = make_uint4(u[4], u[5], u[6], u[7]);
  }
  __syncthreads();

  // Phase 2: waves 0,1 -> 16-image MFMA tiles; waves 2,3 skip to stats
  if (w < 2) {
    const int h  = l >> 4;           // k-group 0..3
    const int li = l & 15;           // class (A) / image (B)
    const int ig = w * 16 + li;      // block-local image for B
    f32x4 acc = {0.0f, 0.0f, 0.0f, 0.0f};
    #pragma unroll
    for (int m = 0; m < 4; ++m) {
      const int r = 2 * m + (h >> 1);                 // pixel row of this fragment
      const bf16x8 a = *(const bf16x8*)&wlds[li][m * 32 + h * 8];
      const bf16x8 b = *(const bf16x8*)&medl[ig][(r ^ (ig & 7)) * 8 + (h & 1) * 4];
      acc = __builtin_amdgcn_mfma_f32_16x16x32_bf16(a, b, acc, 0, 0, 0);
    }
    if (l < 32) {  // C rows 0-7 = classes; rows 8-15 unused
      const size_t io = (size_t)(blockIdx.x * 32 + w * 16 + li) * 8 + h * 4;
      *(float4*)&out[io] = make_float4(acc[0], acc[1], acc[2], acc[3]);
    }
  }

  // stats: wave reduce then block reduce
  #pragma unroll
  for (int off = 32; off; off >>= 1) {
    ssum += __shfl_xor(ssum, off, 64);
    ssq  += __shfl_xor(ssq,  off, 64);
  }
  if (l == 0) { sred[w] = ssum; sred[4 + w] = ssq; }
  __syncthreads();
  if (tid == 0) partial[2 * blockIdx.x]     = (sred[0] + sred[1]) + (sred[2] + sred[3]);
  if (tid == 1) partial[2 * blockIdx.x + 1] = (sred[4] + sred[5]) + (sred[6] + sred[7]);
}

// ---------------------------------------------------------------------------
// K2: each of 256 blocks redundantly reduces partial[8192] (L2-hot),
// recomputes the f32 W' fold for per-class sums, then scales 4 float4/thread:
// out = alpha*dot + (beta*wsum[c] + fcb[c]).
__global__ __launch_bounds__(256) void k_scale(float* __restrict__ out,
                                               const float* __restrict__ partial,
                                               const float* __restrict__ fcw,
                                               const float* __restrict__ xs,
                                               const float* __restrict__ ys,
                                               const float* __restrict__ fcb,
                                               const float* __restrict__ bnw,
                                               const float* __restrict__ bnb) {
  __shared__ float sred[8];
  __shared__ float wred[4][8];
  __shared__ float fin[2];
  const int tid = threadIdx.x;
  const int w = tid >> 6, l = tid & 63;

  float s = 0.0f, q = 0.0f;
  #pragma unroll
  for (int k = 0; k < 16; ++k) {
    const int idx = tid + 256 * k;
    s += partial[2 * idx];
    q += partial[2 * idx + 1];
  }
  #pragma unroll
  for (int off = 32; off; off >>= 1) {
    s += __shfl_xor(s, off, 64);
    q += __shfl_xor(q, off, 64);
  }

  float v[8];
  if (tid < 128) {
    fold_weights(tid, fcw, xs[0] + 0.5f, ys[0] + 0.5f, v);
  } else {
    #pragma unroll
    for (int c = 0; c < 8; ++c) v[c] = 0.0f;
  }
  #pragma unroll
  for (int c = 0; c < 8; ++c) {
    #pragma unroll
    for (int off = 32; off; off >>= 1) v[c] += __shfl_xor(v[c], off, 64);
  }

  if (l == 0) {
    sred[w] = s; sred[4 + w] = q;
    #pragma unroll
    for (int c = 0; c < 8; ++c) wred[w][c] = v[c];
  }
  __syncthreads();
  if (tid == 0) {
    const float S = (sred[0] + sred[1]) + (sred[2] + sred[3]);
    const float Q = (sred[4] + sred[5]) + (sred[6] + sred[7]);
    const float N = 16777216.0f;  // 131072*128
    const float mm = S / N;
    const float vv = Q / N - mm * mm;
    const float a = bnw[0] / sqrtf(vv + 1e-5f);
    fin[0] = a;
    fin[1] = bnb[0] - mm * a;
  }
  __syncthreads();
  const float alpha = fin[0], beta = fin[1];

  float cv[8];
  #pragma unroll
  for (int c = 0; c < 8; ++c) {
    const float wsum = (wred[0][c] + wred[1][c]) + (wred[2][c] + wred[3][c]);
    cv[c] = fmaf(beta, wsum, fcb[c]);
  }
  const float4 cv0 = make_float4(cv[0], cv[1], cv[2], cv[3]);
  const float4 cv1 = make_float4(cv[4], cv[5], cv[6], cv[7]);

  float4* o4 = (float4*)out;
  const int base = (blockIdx.x * 256 + tid) * 4;
  #pragma unroll
  for (int k = 0; k < 4; ++k) {
    const int i = base + k;
    const float4 c = (i & 1) ? cv1 : cv0;
    float4 ov = o4[i];
    ov.x = fmaf(alpha, ov.x, c.x);
    ov.y = fmaf(alpha, ov.y, c.y);
    ov.z = fmaf(alpha, ov.z, c.z);
    ov.w = fmaf(alpha, ov.w, c.w);
    o4[i] = ov;
  }
}

// ---------------------------------------------------------------------------
extern "C" void kernel_launch(void* const* d_in, const int* in_sizes, int n_in,
                              void* d_out, int out_size, void* d_ws, size_t ws_size,
                              hipStream_t stream) {
  const float* x   = (const float*)d_in[0];
  const float* bnw = (const float*)d_in[1];
  const float* bnb = (const float*)d_in[2];
  const float* xs  = (const float*)d_in[3];
  const float* ys  = (const float*)d_in[4];
  const float* fcw = (const float*)d_in[5];
  const float* fcb = (const float*)d_in[6];
  float* out = (float*)d_out;
  float* ws  = (float*)d_ws;

  float* partial = ws;  // 8192 floats

  hipLaunchKernelGGL(k_main,  dim3(NBLK), dim3(256), 0, stream, x, fcw, xs, ys, out, partial);
  hipLaunchKernelGGL(k_scale, dim3(256),  dim3(256), 0, stream, out, partial, fcw, xs, ys, fcb, bnw, bnb);
}